// Round 5
// baseline (488.541 us; speedup 1.0000x reference)
//
#include <hip/hip_runtime.h>
#include <cstdint>
#include <cstring>

// ============================================================================
// NUTS on diagonal Gaussian, exact JAX-semantics replication.
//
// R4 -> R5 change (theory: per-dispatch overhead is work-independent ~40us —
// R3's light k_traj1 (41.0us) == R1's heavy spilled k_traj (42.4us); code
// structure changes R2/R3/R4 all landed ~125us. The lever is DISPATCH COUNT):
//  * ONE fused kernel (k_main) + a tiny counter-zero kernel.
//  * Per-chain "last block finishes the chain" pattern (rocPRIM decoupled
//    style): 16 blocks/chain store dot partials -> __threadfence -> device-
//    scope ACQ_REL fetch_add(done[chain]). The 16th arriver (no spin, no
//    dispatch-order assumption) reduces partials in LDS, runs the template-
//    unrolled NUTS state machine (constexpr stack indices -> registers),
//    then re-simulates its whole chain row to the selected leaf and writes
//    d_out (theta0 row when sel==-1). r0 is saved to ws by phase 1 so the
//    gather phase skips threefry regeneration.
// ============================================================================

#define PARTITIONABLE 1

constexpr int NCHAIN = 128;
constexpr int NDIM   = 16384;
constexpr int VD     = 4;                    // dims per thread (one float4)
constexpr int TPB    = 256;
constexpr int WGPC   = NDIM / (TPB * VD);    // 16 blocks per chain
constexpr int NW     = NDIM / (64 * VD);     // 64 wave-slices per chain
constexpr int NSLOT  = 62;                   // 2*(26 nodes) + 2*(5 doublings)
constexpr int NNODE  = 26;
constexpr float EPS  = 0.05f;

static_assert(NDIM % (TPB * VD) == 0, "tiling");

// ---------------------------------------------------------------- threefry --
__host__ __device__ static inline void tf2(uint32_t k0, uint32_t k1,
                                           uint32_t x0, uint32_t x1,
                                           uint32_t& o0, uint32_t& o1) {
  const uint32_t ks2 = k0 ^ k1 ^ 0x1BD11BDAu;
  x0 += k0; x1 += k1;
#define TF_R(r) { x0 += x1; x1 = (x1 << (r)) | (x1 >> (32 - (r))); x1 ^= x0; }
  TF_R(13) TF_R(15) TF_R(26) TF_R(6)
  x0 += k1;  x1 += ks2 + 1u;
  TF_R(17) TF_R(29) TF_R(16) TF_R(24)
  x0 += ks2; x1 += k0 + 2u;
  TF_R(13) TF_R(15) TF_R(26) TF_R(6)
  x0 += k0;  x1 += k1 + 3u;
  TF_R(17) TF_R(29) TF_R(16) TF_R(24)
  x0 += k1;  x1 += ks2 + 4u;
  TF_R(13) TF_R(15) TF_R(26) TF_R(6)
  x0 += ks2; x1 += k0 + 5u;
#undef TF_R
  o0 = x0; o1 = x1;
}

// uniform [0,1) from 32 random bits, JAX recipe
__device__ static inline float u01(uint32_t bits) {
  return __uint_as_float((bits >> 9) | 0x3f800000u) - 1.0f;
}

// XLA ErfInv32 (Giles), fma-exact
__device__ static inline float erfinv32(float x) {
  float w = -log1pf(-x * x);
  float p;
  if (w < 5.0f) {
    w -= 2.5f;
    p = 2.81022636e-08f;
    p = fmaf(p, w, 3.43273939e-07f);
    p = fmaf(p, w, -3.5233877e-06f);
    p = fmaf(p, w, -4.39150654e-06f);
    p = fmaf(p, w, 0.00021858087f);
    p = fmaf(p, w, -0.00125372503f);
    p = fmaf(p, w, -0.00417768164f);
    p = fmaf(p, w, 0.246640727f);
    p = fmaf(p, w, 1.50140941f);
  } else {
    w = sqrtf(w) - 3.0f;
    p = -0.000200214257f;
    p = fmaf(p, w, 0.000100950558f);
    p = fmaf(p, w, 0.00134934322f);
    p = fmaf(p, w, -0.00367342844f);
    p = fmaf(p, w, 0.00573950773f);
    p = fmaf(p, w, -0.0076224613f);
    p = fmaf(p, w, 0.00943887047f);
    p = fmaf(p, w, 1.00167406f);
    p = fmaf(p, w, 2.83297682f);
  }
  return p * x;
}

// jax.random.normal: u = uniform(lo=nextafter(-1,0), hi=1); hi-lo == 2.0f exactly
__device__ static inline float norm_from_bits(uint32_t bits) {
  const float lo = __uint_as_float(0xBF7FFFFFu);       // -(1 - 2^-24)
  float u = fmaxf(lo, fmaf(u01(bits), 2.0f, lo));
  return __uint_as_float(0x3FB504F3u) * erfinv32(u);   // sqrt(2) in f32
}

// r0 normal for flat element index i of jax.random.normal(kr, (B,D))
__device__ static inline float r0_elem(uint32_t k0, uint32_t k1, uint32_t i) {
#if PARTITIONABLE
  uint32_t a, c; tf2(k0, k1, 0u, i, a, c);
  return norm_from_bits(a ^ c);
#else
  const uint32_t H = (uint32_t)(NCHAIN * NDIM / 2);
  uint32_t a, c;
  if (i < H) { tf2(k0, k1, i, i + H, a, c); return norm_from_bits(a); }
  else       { tf2(k0, k1, i - H, i, a, c); return norm_from_bits(c); }
#endif
}

// one uniform[0,1) for chain b from a (B=128,)-shaped jax.random.uniform
__device__ static inline float unif_chain(uint32_t k0, uint32_t k1, int b) {
#if PARTITIONABLE
  uint32_t a, c; tf2(k0, k1, 0u, (uint32_t)b, a, c);
  return u01(a ^ c);
#else
  uint32_t a, c;
  if (b < 64) { tf2(k0, k1, (uint32_t)b, (uint32_t)(b + 64), a, c); return u01(a); }
  else        { tf2(k0, k1, (uint32_t)(b - 64), (uint32_t)b, a, c); return u01(c); }
#endif
}

// ------------------------------------------------- DPP 64-lane sum (lane 63)
#define DPP_ADD(x, ctrl, rm)                                                   \
  (x) += __int_as_float(__builtin_amdgcn_update_dpp(                           \
      0, __float_as_int(x), (ctrl), (rm), 0xf, true));

__device__ static inline float wave_sum63(float x) {
  DPP_ADD(x, 0x111, 0xf)   // row_shr:1
  DPP_ADD(x, 0x112, 0xf)   // row_shr:2
  DPP_ADD(x, 0x114, 0xf)   // row_shr:4
  DPP_ADD(x, 0x118, 0xf)   // row_shr:8
  DPP_ADD(x, 0x142, 0xa)   // row_bcast:15 -> rows 1,3
  DPP_ADD(x, 0x143, 0xc)   // row_bcast:31 -> rows 2,3
  return x;                // lane 63 holds the 64-lane sum
}

// ------------------------------------------------------------------ params --
struct Params {
  uint32_t nk0[NNODE], nk1[NNODE];  // buildtree k3 keys, post-order across j
  uint32_t ak0[5], ak1[5];          // main-loop ka keys
  int v[5];
};

// --------------------------------------- trajectory state (SROA-friendly) ---
struct St {
  float tha[VD], ra[VD], tho[VD], ro[VD], pc[VD];
  float nt[5][VD], nr[5][VD];       // near-stack: compile-time indexed ONLY
};

// one leaf + its merges; all stack indices constexpr
template <int J, int I>
__device__ __forceinline__ void leaf_body(St& st, const float e, const float he,
                                          float* __restrict__ partials,
                                          const int chain, const int wv,
                                          const int lane, int& slot) {
#pragma unroll
  for (int d = 0; d < VD; ++d) {
    st.ra[d]  = fmaf(-he, st.pc[d] * st.tha[d], st.ra[d]);
    st.tha[d] = fmaf(e, st.ra[d], st.tha[d]);
    st.ra[d]  = fmaf(-he, st.pc[d] * st.tha[d], st.ra[d]);
  }
  constexpr int P = __builtin_popcount((unsigned)I);   // push level
#pragma unroll
  for (int d = 0; d < VD; ++d) { st.nt[P][d] = st.tha[d]; st.nr[P][d] = st.ra[d]; }
  constexpr int M = __builtin_ctz(~(unsigned)I);       // merges after this leaf
#pragma unroll
  for (int k = 0; k < M; ++k) {                        // M<=4, k folds to const
    const int s1 = P - 1 - k;
    float d1 = 0.f, d2 = 0.f;
#pragma unroll
    for (int d = 0; d < VD; ++d) {
      float dd = st.tha[d] - st.nt[s1][d];
      d1 = fmaf(dd, st.nr[s1][d], d1);                 // (th_far-th_near)·r_near
      d2 = fmaf(dd, st.ra[d], d2);                     // (th_far-th_near)·r_far
    }
    d1 = wave_sum63(d1);
    d2 = wave_sum63(d2);
    if (lane == 63) {
      partials[((size_t)(slot    ) * NCHAIN + chain) * NW + wv] = d1;
      partials[((size_t)(slot + 1) * NCHAIN + chain) * NW + wv] = d2;
    }
    slot += 2;
  }
}

template <int J, int I>
__device__ __forceinline__ void run_level(St& st, const float e, const float he,
                                          float* __restrict__ partials,
                                          const int chain, const int wv,
                                          const int lane, int& slot) {
  leaf_body<J, I>(st, e, he, partials, chain, wv, lane, slot);
  if constexpr (I + 1 < (1 << J))
    run_level<J, I + 1>(st, e, he, partials, chain, wv, lane, slot);
}

// -------------------- state machine, template-unrolled (constexpr indices) --
struct SM {
  int n, s, sel, slot, nodeidx, g;
  int st_n[5], st_s[5], st_p[5];    // compile-time indexed ONLY
};

template <int J, int I>
__device__ __forceinline__ void sm_leaf(SM& m, const float* dots_s,
                                        const float* unifs_s, const float vj) {
  constexpr int P = __builtin_popcount((unsigned)I);   // depth before push
  m.st_n[P] = 1; m.st_s[P] = 1; m.st_p[P] = m.g; m.g++;
  constexpr int M = __builtin_ctz(~(unsigned)I);
#pragma unroll
  for (int k = 0; k < M; ++k) {                        // k folds to const
    const int t = P - k;                               // second subtree slot
    int n1 = m.st_n[t-1], s1 = m.st_s[t-1], p1 = m.st_p[t-1];
    int n2 = m.st_n[t],   s2 = m.st_s[t],   p2 = m.st_p[t];
    float d1 = dots_s[m.slot], d2 = dots_s[m.slot + 1];
    m.slot += 2;
    float uu = unifs_s[m.nodeidx]; m.nodeidx++;
    int dn = n1 + n2; if (dn < 1) dn = 1;
    bool fl = (uu < (float)n2 / (float)dn) && (s1 >= 1);
    m.st_p[t-1] = fl ? p2 : p1;
    m.st_s[t-1] = (s1 != 0 && s2 != 0 &&
                   (vj * d1 >= 0.0f) && (vj * d2 >= 0.0f)) ? 1 : 0;
    m.st_n[t-1] = n1 + ((s1 >= 1) ? n2 : 0);
  }
}

template <int J, int I>
__device__ __forceinline__ void sm_level(SM& m, const float* dots_s,
                                         const float* unifs_s, const float vj) {
  sm_leaf<J, I>(m, dots_s, unifs_s, vj);
  if constexpr (I + 1 < (1 << J))
    sm_level<J, I + 1>(m, dots_s, unifs_s, vj);
}

template <int J>
__device__ __forceinline__ void sm_close(SM& m, const float* dots_s,
                                         const float* unifs_s, const int vj) {
  int n_p = m.st_n[0], s_p = m.st_s[0], th_p = m.st_p[0];
  float q1 = dots_s[m.slot], q2 = dots_s[m.slot + 1];  // (a-o)·r_a, (a-o)·r_o
  m.slot += 2;
  float dm1, dm2;                                      // d = (th_f - th_r)
  if (vj > 0) { dm1 = q2;  dm2 = q1; }
  else        { dm1 = -q1; dm2 = -q2; }
  float au = unifs_s[NNODE + J];
  float ratio = fminf((float)n_p / (float)m.n, 1.0f);
  bool acc = (au < ratio) && (m.s >= 1) && (s_p >= 1);
  if (acc) m.sel = th_p;
  m.n = m.n + ((m.s >= 1) ? n_p : 0);
  m.s = (m.s != 0 && s_p != 0 && (dm1 >= 0.0f) && (dm2 >= 0.0f)) ? 1 : 0;
}

// ----------------------------------------------- zero the per-chain counters
__global__ void k_zero(unsigned* __restrict__ done) {
  if (threadIdx.x < NCHAIN) done[threadIdx.x] = 0u;
}

// ------------------------------------------------------- the fused kernel ---
__launch_bounds__(TPB, 2)
__global__ void k_main(const float* __restrict__ th0g, const float* __restrict__ precg,
                       uint32_t kr0, uint32_t kr1,
                       float* __restrict__ partials, float* __restrict__ r0save,
                       unsigned* __restrict__ done, float* __restrict__ outg,
                       Params P) {
  __shared__ float dots_s[NSLOT];
  __shared__ float unifs_s[NNODE + 5];
  __shared__ int   sh_last;

  const int tid     = threadIdx.x;
  const int chain   = blockIdx.x / WGPC;
  const int sblk    = blockIdx.x % WGPC;
  const int dimBase = sblk * (TPB * VD) + tid * VD;
  const int lane    = tid & 63;
  const int wv      = sblk * (TPB / 64) + (tid >> 6);
  const uint32_t flat = (uint32_t)chain * NDIM + dimBase;

  // ====================== phase 1: trajectory + dot partials ================
  {
    St st;
    {
      const float4 t = *reinterpret_cast<const float4*>(th0g + (size_t)chain * NDIM + dimBase);
      const float4 p = *reinterpret_cast<const float4*>(precg + dimBase);
      st.tha[0]=t.x; st.tha[1]=t.y; st.tha[2]=t.z; st.tha[3]=t.w;
      st.pc [0]=p.x; st.pc [1]=p.y; st.pc [2]=p.z; st.pc [3]=p.w;
    }
#pragma unroll
    for (int d = 0; d < VD; ++d) st.ra[d] = r0_elem(kr0, kr1, flat + (uint32_t)d);
    {   // save r0 for the gather phase (skip threefry there)
      float4 r; r.x = st.ra[0]; r.y = st.ra[1]; r.z = st.ra[2]; r.w = st.ra[3];
      *reinterpret_cast<float4*>(r0save + (size_t)flat) = r;
    }
#pragma unroll
    for (int d = 0; d < VD; ++d) { st.tho[d] = st.tha[d]; st.ro[d] = st.ra[d]; }

    int slot = 0;
    bool cur_fwd = true;

#define LEVEL(J)                                                               \
    {                                                                          \
      const bool fwd = P.v[J] > 0;                                             \
      if (fwd != cur_fwd) {                                                    \
        _Pragma("unroll")                                                      \
        for (int d = 0; d < VD; ++d) {                                         \
          float t;                                                             \
          t = st.tha[d]; st.tha[d] = st.tho[d]; st.tho[d] = t;                 \
          t = st.ra[d];  st.ra[d]  = st.ro[d];  st.ro[d]  = t;                 \
        }                                                                      \
      }                                                                        \
      cur_fwd = fwd;                                                           \
      const float e  = fwd ? EPS : -EPS;                                       \
      const float he = 0.5f * e;                                               \
      run_level<J, 0>(st, e, he, partials, chain, wv, lane, slot);             \
      float p1 = 0.f, p2 = 0.f;                                                \
      _Pragma("unroll")                                                        \
      for (int d = 0; d < VD; ++d) {                                           \
        float dd = st.tha[d] - st.tho[d];                                      \
        p1 = fmaf(dd, st.ra[d], p1);                                           \
        p2 = fmaf(dd, st.ro[d], p2);                                           \
      }                                                                        \
      p1 = wave_sum63(p1);                                                     \
      p2 = wave_sum63(p2);                                                     \
      if (lane == 63) {                                                        \
        partials[((size_t)(slot    ) * NCHAIN + chain) * NW + wv] = p1;        \
        partials[((size_t)(slot + 1) * NCHAIN + chain) * NW + wv] = p2;        \
      }                                                                        \
      slot += 2;                                                               \
    }

    LEVEL(0) LEVEL(1) LEVEL(2) LEVEL(3) LEVEL(4)
#undef LEVEL
  }

  // ====================== arrival: last block of this chain proceeds ========
  __threadfence();                       // make this thread's stores device-visible
  __syncthreads();                       // join all threads' fences
  if (tid == 0) {
    unsigned old = __hip_atomic_fetch_add(&done[chain], 1u,
                                          __ATOMIC_ACQ_REL, __HIP_MEMORY_SCOPE_AGENT);
    sh_last = (old == (unsigned)(WGPC - 1));
  }
  __syncthreads();
  if (!sh_last) return;
  __threadfence();                       // acquire side: invalidate stale cache

  // ====================== phase 2: reduce + state machine ===================
  if (tid < NNODE) unifs_s[tid] = unif_chain(P.nk0[tid], P.nk1[tid], chain);
  else if (tid < NNODE + 5)
    unifs_s[tid] = unif_chain(P.ak0[tid - NNODE], P.ak1[tid - NNODE], chain);

  for (int s = (tid >> 6); s < NSLOT; s += TPB / 64) {
    float v = partials[((size_t)s * NCHAIN + chain) * NW + lane];
    v = wave_sum63(v);
    if (lane == 63) dots_s[s] = v;
  }
  __syncthreads();

  SM m;
  m.n = 1; m.s = 1; m.sel = -1; m.slot = 0; m.nodeidx = 0; m.g = 0;
#define SLEVEL(J)                                                              \
  {                                                                            \
    const float vj = (P.v[J] > 0) ? 1.0f : -1.0f;                              \
    sm_level<J, 0>(m, dots_s, unifs_s, vj);                                    \
    sm_close<J>(m, dots_s, unifs_s, P.v[J]);                                   \
  }
  SLEVEL(0) SLEVEL(1) SLEVEL(2) SLEVEL(3) SLEVEL(4)
#undef SLEVEL
  const int sel = m.sel;

  // ====================== phase 3: gather the whole chain row ===============
  for (int grp = 0; grp < WGPC; ++grp) {
    const int db = grp * (TPB * VD) + tid * VD;
    const size_t off = (size_t)chain * NDIM + db;
    float tha[VD], ra[VD], tho[VD], ro[VD], pc[VD], outv[VD];
    {
      const float4 t = *reinterpret_cast<const float4*>(th0g + off);
      tha[0]=t.x; tha[1]=t.y; tha[2]=t.z; tha[3]=t.w;
    }
#pragma unroll
    for (int d = 0; d < VD; ++d) outv[d] = tha[d];     // default: theta0
    if (sel >= 0) {
      const float4 p = *reinterpret_cast<const float4*>(precg + db);
      const float4 r = *reinterpret_cast<const float4*>(r0save + off);
      pc[0]=p.x; pc[1]=p.y; pc[2]=p.z; pc[3]=p.w;
      ra[0]=r.x; ra[1]=r.y; ra[2]=r.z; ra[3]=r.w;
#pragma unroll
      for (int d = 0; d < VD; ++d) { tho[d] = tha[d]; ro[d] = ra[d]; }
      int g = 0;
      bool cur_fwd = true;
      bool fin = false;
      for (int j = 0; j < 5 && !fin; ++j) {
        const bool fwd = P.v[j] > 0;
        if (fwd != cur_fwd) {
#pragma unroll
          for (int d = 0; d < VD; ++d) {
            float t;
            t = tha[d]; tha[d] = tho[d]; tho[d] = t;
            t = ra[d];  ra[d]  = ro[d];  ro[d]  = t;
          }
        }
        cur_fwd = fwd;
        const float e  = fwd ? EPS : -EPS;
        const float he = 0.5f * e;
        const int NL = 1 << j;
        for (int i = 0; i < NL; ++i) {
#pragma unroll
          for (int d = 0; d < VD; ++d) {
            ra[d]  = fmaf(-he, pc[d] * tha[d], ra[d]);
            tha[d] = fmaf(e, ra[d], tha[d]);
            ra[d]  = fmaf(-he, pc[d] * tha[d], ra[d]);
          }
          if (g == sel) {
#pragma unroll
            for (int d = 0; d < VD; ++d) outv[d] = tha[d];
            fin = true;
            break;
          }
          g++;
        }
      }
    }
    float4 o; o.x = outv[0]; o.y = outv[1]; o.z = outv[2]; o.w = outv[3];
    *reinterpret_cast<float4*>(outg + off) = o;
  }
}

// ------------------------------------------------------------- host PRNG ---
static inline float host_bits_to_f(uint32_t fb) { float f; std::memcpy(&f, &fb, 4); return f; }

static void host_split(uint32_t k0, uint32_t k1, int nsub, uint32_t* o0, uint32_t* o1) {
#if PARTITIONABLE
  for (int i = 0; i < nsub; ++i) tf2(k0, k1, 0u, (uint32_t)i, o0[i], o1[i]);
#else
  uint32_t A[8], C[8], flat[16];
  for (int i = 0; i < nsub; ++i) tf2(k0, k1, (uint32_t)i, (uint32_t)(nsub + i), A[i], C[i]);
  for (int i = 0; i < nsub; ++i) { flat[i] = A[i]; flat[nsub + i] = C[i]; }
  for (int j = 0; j < nsub; ++j) { o0[j] = flat[2*j]; o1[j] = flat[2*j + 1]; }
#endif
}

static int host_vsign(uint32_t k0, uint32_t k1) {    // sign of normal(kv, ())
  uint32_t a, c; tf2(k0, k1, 0u, 0u, a, c);
#if PARTITIONABLE
  uint32_t bits = a ^ c;
#else
  uint32_t bits = a;
#endif
  float f  = host_bits_to_f((bits >> 9) | 0x3f800000u) - 1.0f;
  float lo = host_bits_to_f(0xBF7FFFFFu);
  float u  = f * 2.0f + lo;                          // sign(erfinv(u)) = sign(u)
  return (u >= 0.0f) ? 1 : -1;
}

// buildtree k3 keys in post-order (merge-consumption order)
static void gen_nodes(uint32_t k0, uint32_t k1, int j,
                      uint32_t* nk0, uint32_t* nk1, int& idx) {
  if (j == 0) return;
  uint32_t o0[3], o1[3];
  host_split(k0, k1, 3, o0, o1);                     // k1, k2, k3
  gen_nodes(o0[0], o1[0], j - 1, nk0, nk1, idx);
  gen_nodes(o0[1], o1[1], j - 1, nk0, nk1, idx);
  nk0[idx] = o0[2]; nk1[idx] = o1[2]; idx++;
}

// ---------------------------------------------------------------- launch ----
extern "C" void kernel_launch(void* const* d_in, const int* in_sizes, int n_in,
                              void* d_out, int out_size, void* d_ws, size_t ws_size,
                              hipStream_t stream) {
  const float* th0  = (const float*)d_in[0];
  const float* prec = (const float*)d_in[1];
  float* out = (float*)d_out;

  float*    partials = (float*)d_ws;                                // ~2 MB
  float*    r0save   = partials + (size_t)NSLOT * NCHAIN * NW;      // 8 MB
  unsigned* done     = (unsigned*)(r0save + (size_t)NCHAIN * NDIM); // 512 B

  // ---- replicate jax key schedule on host (deterministic, same every call)
  uint32_t key0 = 0u, key1 = 42u;                               // jax.random.key(42)
  uint32_t s0[4], s1[4];
  host_split(key0, key1, 3, s0, s1);                            // kr, ku, key
  const uint32_t kr0 = s0[0], kr1 = s1[0];                      // r0 normals
  key0 = s0[2]; key1 = s1[2];                                   // (ku unused: u==0)

  Params P;
  int idx = 0;
  for (int j = 0; j < 5; ++j) {
    host_split(key0, key1, 4, s0, s1);                          // key, kv, kt, ka
    key0 = s0[0]; key1 = s1[0];
    P.v[j] = host_vsign(s0[1], s1[1]);
    gen_nodes(s0[2], s1[2], j, P.nk0, P.nk1, idx);              // kt recursion
    P.ak0[j] = s0[3]; P.ak1[j] = s1[3];                         // ka
  }

  k_zero<<<dim3(1), dim3(NCHAIN), 0, stream>>>(done);
  k_main<<<dim3(NCHAIN * WGPC), dim3(TPB), 0, stream>>>(
      th0, prec, kr0, kr1, partials, r0save, done, out, P);
}

// Round 6
// 116.323 us; speedup vs baseline: 4.1999x; 4.1999x over previous
//
#include <hip/hip_runtime.h>
#include <cstdint>
#include <cstring>

// ============================================================================
// NUTS on diagonal Gaussian, exact JAX-semantics replication.
//
// R5 -> R6 (theory: EVERY round's kernels compiled to VGPR 20-32 => local
// arrays never left scratch. SROA runs BEFORE loop unrolling; any array
// access with a loop-variable index (the d-loops, the merge k-loop) keeps
// the whole alloca in scratch => each leapfrog step is a ~300cy dependent
// scratch round-trip. R5's serial tail made it 373us; it was always there.)
//  * NO local arrays anywhere: state is named float4 vars; near-stack and
//    SM stack are named members behind `if constexpr` getters; merge loops
//    are template recursion. Every index is constant at parse time.
//  * Parallel 3-kernel structure (no atomics): k_traj0 (2048 blk) ->
//    k_logic (128 blk: reduce + state machine) -> k_gather (2048 blk).
// ============================================================================

#define PARTITIONABLE 1

constexpr int NCHAIN = 128;
constexpr int NDIM   = 16384;
constexpr int TPB    = 256;
constexpr int WGPC   = NDIM / (TPB * 4);     // 16 blocks per chain
constexpr int NW     = NDIM / (64 * 4);      // 64 wave-slices per chain
constexpr int NSLOT  = 62;                   // 2*(26 nodes) + 2*(5 doublings)
constexpr int NNODE  = 26;
constexpr float EPS  = 0.05f;

// ---------------------------------------------------------------- threefry --
__host__ __device__ static inline void tf2(uint32_t k0, uint32_t k1,
                                           uint32_t x0, uint32_t x1,
                                           uint32_t& o0, uint32_t& o1) {
  const uint32_t ks2 = k0 ^ k1 ^ 0x1BD11BDAu;
  x0 += k0; x1 += k1;
#define TF_R(r) { x0 += x1; x1 = (x1 << (r)) | (x1 >> (32 - (r))); x1 ^= x0; }
  TF_R(13) TF_R(15) TF_R(26) TF_R(6)
  x0 += k1;  x1 += ks2 + 1u;
  TF_R(17) TF_R(29) TF_R(16) TF_R(24)
  x0 += ks2; x1 += k0 + 2u;
  TF_R(13) TF_R(15) TF_R(26) TF_R(6)
  x0 += k0;  x1 += k1 + 3u;
  TF_R(17) TF_R(29) TF_R(16) TF_R(24)
  x0 += k1;  x1 += ks2 + 4u;
  TF_R(13) TF_R(15) TF_R(26) TF_R(6)
  x0 += ks2; x1 += k0 + 5u;
#undef TF_R
  o0 = x0; o1 = x1;
}

__device__ static inline float u01(uint32_t bits) {
  return __uint_as_float((bits >> 9) | 0x3f800000u) - 1.0f;
}

// XLA ErfInv32 (Giles), fma-exact
__device__ static inline float erfinv32(float x) {
  float w = -log1pf(-x * x);
  float p;
  if (w < 5.0f) {
    w -= 2.5f;
    p = 2.81022636e-08f;
    p = fmaf(p, w, 3.43273939e-07f);
    p = fmaf(p, w, -3.5233877e-06f);
    p = fmaf(p, w, -4.39150654e-06f);
    p = fmaf(p, w, 0.00021858087f);
    p = fmaf(p, w, -0.00125372503f);
    p = fmaf(p, w, -0.00417768164f);
    p = fmaf(p, w, 0.246640727f);
    p = fmaf(p, w, 1.50140941f);
  } else {
    w = sqrtf(w) - 3.0f;
    p = -0.000200214257f;
    p = fmaf(p, w, 0.000100950558f);
    p = fmaf(p, w, 0.00134934322f);
    p = fmaf(p, w, -0.00367342844f);
    p = fmaf(p, w, 0.00573950773f);
    p = fmaf(p, w, -0.0076224613f);
    p = fmaf(p, w, 0.00943887047f);
    p = fmaf(p, w, 1.00167406f);
    p = fmaf(p, w, 2.83297682f);
  }
  return p * x;
}

__device__ static inline float norm_from_bits(uint32_t bits) {
  const float lo = __uint_as_float(0xBF7FFFFFu);       // -(1 - 2^-24)
  float u = fmaxf(lo, fmaf(u01(bits), 2.0f, lo));
  return __uint_as_float(0x3FB504F3u) * erfinv32(u);   // sqrt(2) in f32
}

__device__ static inline float r0_elem(uint32_t k0, uint32_t k1, uint32_t i) {
#if PARTITIONABLE
  uint32_t a, c; tf2(k0, k1, 0u, i, a, c);
  return norm_from_bits(a ^ c);
#else
  const uint32_t H = (uint32_t)(NCHAIN * NDIM / 2);
  uint32_t a, c;
  if (i < H) { tf2(k0, k1, i, i + H, a, c); return norm_from_bits(a); }
  else       { tf2(k0, k1, i - H, i, a, c); return norm_from_bits(c); }
#endif
}

__device__ static inline float unif_chain(uint32_t k0, uint32_t k1, int b) {
#if PARTITIONABLE
  uint32_t a, c; tf2(k0, k1, 0u, (uint32_t)b, a, c);
  return u01(a ^ c);
#else
  uint32_t a, c;
  if (b < 64) { tf2(k0, k1, (uint32_t)b, (uint32_t)(b + 64), a, c); return u01(a); }
  else        { tf2(k0, k1, (uint32_t)(b - 64), (uint32_t)b, a, c); return u01(c); }
#endif
}

// ------------------------------------------------- DPP 64-lane sum (lane 63)
#define DPP_ADD(x, ctrl, rm)                                                   \
  (x) += __int_as_float(__builtin_amdgcn_update_dpp(                           \
      0, __float_as_int(x), (ctrl), (rm), 0xf, true));

__device__ static inline float wave_sum63(float x) {
  DPP_ADD(x, 0x111, 0xf)   // row_shr:1
  DPP_ADD(x, 0x112, 0xf)   // row_shr:2
  DPP_ADD(x, 0x114, 0xf)   // row_shr:4
  DPP_ADD(x, 0x118, 0xf)   // row_shr:8
  DPP_ADD(x, 0x142, 0xa)   // row_bcast:15 -> rows 1,3
  DPP_ADD(x, 0x143, 0xc)   // row_bcast:31 -> rows 2,3
  return x;                // lane 63 holds the 64-lane sum
}

// ------------------------------------------------------- float4 arithmetic --
__device__ __forceinline__ float4 f4_pcfma(float he, const float4& pc,
                                           const float4& th, const float4& r) {
  // r + he*(pc*th), componentwise
  return make_float4(fmaf(he, pc.x * th.x, r.x), fmaf(he, pc.y * th.y, r.y),
                     fmaf(he, pc.z * th.z, r.z), fmaf(he, pc.w * th.w, r.w));
}
__device__ __forceinline__ float4 f4_fma(float e, const float4& a, const float4& b) {
  return make_float4(fmaf(e, a.x, b.x), fmaf(e, a.y, b.y),
                     fmaf(e, a.z, b.z), fmaf(e, a.w, b.w));
}
__device__ __forceinline__ float f4_dotsub(const float4& a, const float4& b,
                                           const float4& r) {
  // sum((a-b)*r)
  float d = (a.x - b.x) * r.x;
  d = fmaf(a.y - b.y, r.y, d);
  d = fmaf(a.z - b.z, r.z, d);
  d = fmaf(a.w - b.w, r.w, d);
  return d;
}

// ------------------------------------------------------------------ params --
struct Params {
  uint32_t nk0[NNODE], nk1[NNODE];  // buildtree k3 keys, post-order across j
  uint32_t ak0[5], ak1[5];          // main-loop ka keys
  int v[5];
};

// ------------------------------- trajectory state: NAMED float4 vars only ---
struct Traj {
  float4 th, r, tho, ro, pc;
  float4 nt0, nt1, nt2, nt3, nt4;
  float4 nr0, nr1, nr2, nr3, nr4;
};
template <int L> __device__ __forceinline__ float4& NT(Traj& t) {
  if constexpr (L == 0) return t.nt0; else if constexpr (L == 1) return t.nt1;
  else if constexpr (L == 2) return t.nt2; else if constexpr (L == 3) return t.nt3;
  else return t.nt4;
}
template <int L> __device__ __forceinline__ float4& NR(Traj& t) {
  if constexpr (L == 0) return t.nr0; else if constexpr (L == 1) return t.nr1;
  else if constexpr (L == 2) return t.nr2; else if constexpr (L == 3) return t.nr3;
  else return t.nr4;
}

// merges after a leaf: K = 0..M-1, all indices constexpr
template <int P, int K, int M>
struct Merge {
  static __device__ __forceinline__ void run(Traj& t, float* __restrict__ partials,
                                             int chain, int wv, int lane, int& slot) {
    if constexpr (K < M) {
      const float4& nt = NT<P - 1 - K>(t);
      const float4& nr = NR<P - 1 - K>(t);
      float d1 = f4_dotsub(t.th, nt, nr);     // (th_far-th_near)·r_near
      float d2 = f4_dotsub(t.th, nt, t.r);    // (th_far-th_near)·r_far
      d1 = wave_sum63(d1);
      d2 = wave_sum63(d2);
      if (lane == 63) {
        partials[((size_t)(slot    ) * NCHAIN + chain) * NW + wv] = d1;
        partials[((size_t)(slot + 1) * NCHAIN + chain) * NW + wv] = d2;
      }
      slot += 2;
      Merge<P, K + 1, M>::run(t, partials, chain, wv, lane, slot);
    }
  }
};

template <int J, int I>
struct Leaf {
  static __device__ __forceinline__ void run(Traj& t, float e, float he,
                                             float* __restrict__ partials,
                                             int chain, int wv, int lane, int& slot) {
    t.r  = f4_pcfma(-he, t.pc, t.th, t.r);
    t.th = f4_fma(e, t.r, t.th);
    t.r  = f4_pcfma(-he, t.pc, t.th, t.r);
    constexpr int P = __builtin_popcount((unsigned)I);
    NT<P>(t) = t.th; NR<P>(t) = t.r;
    constexpr int M = __builtin_ctz(~(unsigned)I);
    Merge<P, 0, M>::run(t, partials, chain, wv, lane, slot);
    if constexpr (I + 1 < (1 << J))
      Leaf<J, I + 1>::run(t, e, he, partials, chain, wv, lane, slot);
  }
};

// ----------------------------------------------- K1: trajectory, dots mode --
__launch_bounds__(TPB)
__global__ void k_traj0(const float* __restrict__ th0g, const float* __restrict__ precg,
                        uint32_t kr0, uint32_t kr1,
                        float* __restrict__ partials, Params P) {
  const int tid     = threadIdx.x;
  const int chain   = blockIdx.x / WGPC;
  const int sblk    = blockIdx.x % WGPC;
  const int dimBase = sblk * (TPB * 4) + tid * 4;
  const int lane    = tid & 63;
  const int wv      = sblk * (TPB / 64) + (tid >> 6);
  const uint32_t flat = (uint32_t)chain * NDIM + dimBase;

  Traj t;
  t.th = *reinterpret_cast<const float4*>(th0g + (size_t)chain * NDIM + dimBase);
  t.pc = *reinterpret_cast<const float4*>(precg + dimBase);
  t.r.x = r0_elem(kr0, kr1, flat + 0u);
  t.r.y = r0_elem(kr0, kr1, flat + 1u);
  t.r.z = r0_elem(kr0, kr1, flat + 2u);
  t.r.w = r0_elem(kr0, kr1, flat + 3u);
  t.tho = t.th; t.ro = t.r;

  int slot = 0;
  bool cur_fwd = true;

#define LEVEL(J)                                                               \
  {                                                                            \
    const bool fwd = P.v[J] > 0;                                               \
    if (fwd != cur_fwd) {                                                      \
      float4 tmp;                                                              \
      tmp = t.th; t.th = t.tho; t.tho = tmp;                                   \
      tmp = t.r;  t.r  = t.ro;  t.ro  = tmp;                                   \
    }                                                                          \
    cur_fwd = fwd;                                                             \
    const float e  = fwd ? EPS : -EPS;                                         \
    const float he = 0.5f * e;                                                 \
    Leaf<J, 0>::run(t, e, he, partials, chain, wv, lane, slot);                \
    float p1 = f4_dotsub(t.th, t.tho, t.r);                                    \
    float p2 = f4_dotsub(t.th, t.tho, t.ro);                                   \
    p1 = wave_sum63(p1);                                                       \
    p2 = wave_sum63(p2);                                                       \
    if (lane == 63) {                                                          \
      partials[((size_t)(slot    ) * NCHAIN + chain) * NW + wv] = p1;          \
      partials[((size_t)(slot + 1) * NCHAIN + chain) * NW + wv] = p2;          \
    }                                                                          \
    slot += 2;                                                                 \
  }

  LEVEL(0) LEVEL(1) LEVEL(2) LEVEL(3) LEVEL(4)
#undef LEVEL
}

// ------------------------- state machine: NAMED scalar slots + templates ----
struct SMs {
  int n0, s0, p0, n1, s1, p1, n2, s2, p2, n3, s3, p3, n4, s4, p4;
  int n, s, sel, slot, nodeidx, g;
};
template <int L> __device__ __forceinline__ int& SN(SMs& m) {
  if constexpr (L == 0) return m.n0; else if constexpr (L == 1) return m.n1;
  else if constexpr (L == 2) return m.n2; else if constexpr (L == 3) return m.n3;
  else return m.n4;
}
template <int L> __device__ __forceinline__ int& SS(SMs& m) {
  if constexpr (L == 0) return m.s0; else if constexpr (L == 1) return m.s1;
  else if constexpr (L == 2) return m.s2; else if constexpr (L == 3) return m.s3;
  else return m.s4;
}
template <int L> __device__ __forceinline__ int& SP(SMs& m) {
  if constexpr (L == 0) return m.p0; else if constexpr (L == 1) return m.p1;
  else if constexpr (L == 2) return m.p2; else if constexpr (L == 3) return m.p3;
  else return m.p4;
}

template <int P, int K, int M>
struct SMerge {
  static __device__ __forceinline__ void run(SMs& m, const float* dots_s,
                                             const float* unifs_s, float vj) {
    if constexpr (K < M) {
      constexpr int T = P - K;                       // second subtree slot
      int n1 = SN<T-1>(m), s1 = SS<T-1>(m), p1 = SP<T-1>(m);
      int n2 = SN<T>(m),   s2 = SS<T>(m),   p2 = SP<T>(m);
      float d1 = dots_s[m.slot], d2 = dots_s[m.slot + 1];
      m.slot += 2;
      float uu = unifs_s[m.nodeidx]; m.nodeidx++;
      int dn = n1 + n2; if (dn < 1) dn = 1;
      bool fl = (uu < (float)n2 / (float)dn) && (s1 >= 1);
      SP<T-1>(m) = fl ? p2 : p1;
      SS<T-1>(m) = (s1 != 0 && s2 != 0 &&
                    (vj * d1 >= 0.0f) && (vj * d2 >= 0.0f)) ? 1 : 0;
      SN<T-1>(m) = n1 + ((s1 >= 1) ? n2 : 0);
      SMerge<P, K + 1, M>::run(m, dots_s, unifs_s, vj);
    }
  }
};

template <int J, int I>
struct SLeaf {
  static __device__ __forceinline__ void run(SMs& m, const float* dots_s,
                                             const float* unifs_s, float vj) {
    constexpr int P = __builtin_popcount((unsigned)I);
    SN<P>(m) = 1; SS<P>(m) = 1; SP<P>(m) = m.g; m.g++;
    constexpr int M = __builtin_ctz(~(unsigned)I);
    SMerge<P, 0, M>::run(m, dots_s, unifs_s, vj);
    if constexpr (I + 1 < (1 << J))
      SLeaf<J, I + 1>::run(m, dots_s, unifs_s, vj);
  }
};

template <int J>
__device__ __forceinline__ void sm_close(SMs& m, const float* dots_s,
                                         const float* unifs_s, int vj) {
  int n_p = SN<0>(m), s_p = SS<0>(m), th_p = SP<0>(m);
  float q1 = dots_s[m.slot], q2 = dots_s[m.slot + 1];  // (a-o)·r_a, (a-o)·r_o
  m.slot += 2;
  float dm1, dm2;                                      // d = (th_f - th_r)
  if (vj > 0) { dm1 = q2;  dm2 = q1; }
  else        { dm1 = -q1; dm2 = -q2; }
  float au = unifs_s[NNODE + J];
  float ratio = fminf((float)n_p / (float)m.n, 1.0f);
  bool acc = (au < ratio) && (m.s >= 1) && (s_p >= 1);
  if (acc) m.sel = th_p;
  m.n = m.n + ((m.s >= 1) ? n_p : 0);
  m.s = (m.s != 0 && s_p != 0 && (dm1 >= 0.0f) && (dm2 >= 0.0f)) ? 1 : 0;
}

// --------------------- K2: per-chain reduce + state machine (128 blocks) ----
__launch_bounds__(TPB)
__global__ void k_logic(const float* __restrict__ partials, int* __restrict__ selg,
                        Params P) {
  __shared__ float dots_s[NSLOT];
  __shared__ float unifs_s[NNODE + 5];
  const int chain = blockIdx.x;
  const int tid   = threadIdx.x;
  const int lane  = tid & 63;
  const int w     = tid >> 6;

  for (int s = w; s < NSLOT; s += TPB / 64) {
    float v = partials[((size_t)s * NCHAIN + chain) * NW + lane];
    v = wave_sum63(v);
    if (lane == 63) dots_s[s] = v;
  }
  if (tid < NNODE) unifs_s[tid] = unif_chain(P.nk0[tid], P.nk1[tid], chain);
  else if (tid < NNODE + 5)
    unifs_s[tid] = unif_chain(P.ak0[tid - NNODE], P.ak1[tid - NNODE], chain);
  __syncthreads();

  if (tid == 0) {
    SMs m;
    m.n = 1; m.s = 1; m.sel = -1; m.slot = 0; m.nodeidx = 0; m.g = 0;
#define SLEVEL(J)                                                              \
    {                                                                          \
      const float vj = (P.v[J] > 0) ? 1.0f : -1.0f;                            \
      SLeaf<J, 0>::run(m, dots_s, unifs_s, vj);                                \
      sm_close<J>(m, dots_s, unifs_s, P.v[J]);                                 \
    }
    SLEVEL(0) SLEVEL(1) SLEVEL(2) SLEVEL(3) SLEVEL(4)
#undef SLEVEL
    selg[chain] = m.sel;
  }
}

// -------------------- K3: gather — re-simulate to selected leaf, write ------
__launch_bounds__(TPB)
__global__ void k_gather(const float* __restrict__ th0g, const float* __restrict__ precg,
                         uint32_t kr0, uint32_t kr1,
                         const int* __restrict__ selg, float* __restrict__ outg,
                         Params P) {
  const int tid     = threadIdx.x;
  const int chain   = blockIdx.x / WGPC;
  const int sblk    = blockIdx.x % WGPC;
  const int dimBase = sblk * (TPB * 4) + tid * 4;
  const size_t off  = (size_t)chain * NDIM + dimBase;
  const uint32_t flat = (uint32_t)off;
  const int sel = selg[chain];                         // wave-uniform

  float4 th = *reinterpret_cast<const float4*>(th0g + off);
  float4 outv = th;                                    // default: theta0
  if (sel >= 0) {
    float4 pc = *reinterpret_cast<const float4*>(precg + dimBase);
    float4 r;
    r.x = r0_elem(kr0, kr1, flat + 0u);
    r.y = r0_elem(kr0, kr1, flat + 1u);
    r.z = r0_elem(kr0, kr1, flat + 2u);
    r.w = r0_elem(kr0, kr1, flat + 3u);
    float4 tho = th, ro = r;
    int g = 0;
    bool cur_fwd = true;
    bool fin = false;
    for (int j = 0; j < 5 && !fin; ++j) {
      const bool fwd = P.v[j] > 0;
      if (fwd != cur_fwd) {
        float4 tmp;
        tmp = th; th = tho; tho = tmp;
        tmp = r;  r  = ro;  ro  = tmp;
      }
      cur_fwd = fwd;
      const float e  = fwd ? EPS : -EPS;
      const float he = 0.5f * e;
      const int NL = 1 << j;
      for (int i = 0; i < NL; ++i) {
        r  = f4_pcfma(-he, pc, th, r);
        th = f4_fma(e, r, th);
        r  = f4_pcfma(-he, pc, th, r);
        if (g == sel) { outv = th; fin = true; break; }
        g++;
      }
    }
  }
  *reinterpret_cast<float4*>(outg + off) = outv;
}

// ------------------------------------------------------------- host PRNG ---
static inline float host_bits_to_f(uint32_t fb) { float f; std::memcpy(&f, &fb, 4); return f; }

static void host_split(uint32_t k0, uint32_t k1, int nsub, uint32_t* o0, uint32_t* o1) {
#if PARTITIONABLE
  for (int i = 0; i < nsub; ++i) tf2(k0, k1, 0u, (uint32_t)i, o0[i], o1[i]);
#else
  uint32_t A[8], C[8], flat[16];
  for (int i = 0; i < nsub; ++i) tf2(k0, k1, (uint32_t)i, (uint32_t)(nsub + i), A[i], C[i]);
  for (int i = 0; i < nsub; ++i) { flat[i] = A[i]; flat[nsub + i] = C[i]; }
  for (int j = 0; j < nsub; ++j) { o0[j] = flat[2*j]; o1[j] = flat[2*j + 1]; }
#endif
}

static int host_vsign(uint32_t k0, uint32_t k1) {    // sign of normal(kv, ())
  uint32_t a, c; tf2(k0, k1, 0u, 0u, a, c);
#if PARTITIONABLE
  uint32_t bits = a ^ c;
#else
  uint32_t bits = a;
#endif
  float f  = host_bits_to_f((bits >> 9) | 0x3f800000u) - 1.0f;
  float lo = host_bits_to_f(0xBF7FFFFFu);
  float u  = f * 2.0f + lo;                          // sign(erfinv(u)) = sign(u)
  return (u >= 0.0f) ? 1 : -1;
}

// buildtree k3 keys in post-order (merge-consumption order)
static void gen_nodes(uint32_t k0, uint32_t k1, int j,
                      uint32_t* nk0, uint32_t* nk1, int& idx) {
  if (j == 0) return;
  uint32_t o0[3], o1[3];
  host_split(k0, k1, 3, o0, o1);                     // k1, k2, k3
  gen_nodes(o0[0], o1[0], j - 1, nk0, nk1, idx);
  gen_nodes(o0[1], o1[1], j - 1, nk0, nk1, idx);
  nk0[idx] = o0[2]; nk1[idx] = o1[2]; idx++;
}

// ---------------------------------------------------------------- launch ----
extern "C" void kernel_launch(void* const* d_in, const int* in_sizes, int n_in,
                              void* d_out, int out_size, void* d_ws, size_t ws_size,
                              hipStream_t stream) {
  const float* th0  = (const float*)d_in[0];
  const float* prec = (const float*)d_in[1];
  float* out = (float*)d_out;

  float* partials = (float*)d_ws;                               // ~2 MB
  int*   sel      = (int*)(partials + (size_t)NSLOT * NCHAIN * NW);

  // ---- replicate jax key schedule on host (deterministic, same every call)
  uint32_t key0 = 0u, key1 = 42u;                               // jax.random.key(42)
  uint32_t s0[4], s1[4];
  host_split(key0, key1, 3, s0, s1);                            // kr, ku, key
  const uint32_t kr0 = s0[0], kr1 = s1[0];                      // r0 normals
  key0 = s0[2]; key1 = s1[2];                                   // (ku unused: u==0)

  Params P;
  int idx = 0;
  for (int j = 0; j < 5; ++j) {
    host_split(key0, key1, 4, s0, s1);                          // key, kv, kt, ka
    key0 = s0[0]; key1 = s1[0];
    P.v[j] = host_vsign(s0[1], s1[1]);
    gen_nodes(s0[2], s1[2], j, P.nk0, P.nk1, idx);              // kt recursion
    P.ak0[j] = s0[3]; P.ak1[j] = s1[3];                         // ka
  }

  k_traj0<<<dim3(NCHAIN * WGPC), dim3(TPB), 0, stream>>>(
      th0, prec, kr0, kr1, partials, P);
  k_logic<<<dim3(NCHAIN), dim3(TPB), 0, stream>>>(partials, sel, P);
  k_gather<<<dim3(NCHAIN * WGPC), dim3(TPB), 0, stream>>>(
      th0, prec, kr0, kr1, sel, out, P);
}

// Round 7
// 108.641 us; speedup vs baseline: 4.4968x; 1.0707x over previous
//
#include <hip/hip_runtime.h>
#include <cstdint>
#include <cstring>

// ============================================================================
// NUTS on diagonal Gaussian, exact JAX-semantics replication.
//
// R6 -> R7 (theory: kernels now sub-fill (<41.8us) but total still ~70us over
// the ~46-50us harness poison/restore floor; attack dispatch count + the
// biggest instruction block in k_traj0):
//  * 2 dispatches: k_traj0 -> k_gather. k_gather redundantly reduces its
//    chain's partials in LDS + runs the state machine on all threads (no
//    k_logic, no atomics; partials read-only after the graph edge).
//  * k_traj0 merge reduction: wave_sum63 (12 DPP) -> wave_sum15 (4 DPP,
//    row-of-16 sums, 4 partials/wave). ~500 fewer inst/thread.
//  * r0 saved to ws by k_traj0; k_gather loads it (skips threefry+erfinv).
//  * __launch_bounds__(256,4) on both (VGPR cap 128, >=4 blocks/CU).
// ============================================================================

#define PARTITIONABLE 1

constexpr int NCHAIN = 128;
constexpr int NDIM   = 16384;
constexpr int TPB    = 256;
constexpr int WGPC   = NDIM / (TPB * 4);     // 16 blocks per chain
constexpr int NP     = 256;                  // partial slots per chain-slot
constexpr int NSLOT  = 62;                   // 2*(26 nodes) + 2*(5 doublings)
constexpr int NNODE  = 26;
constexpr float EPS  = 0.05f;

// ---------------------------------------------------------------- threefry --
__host__ __device__ static inline void tf2(uint32_t k0, uint32_t k1,
                                           uint32_t x0, uint32_t x1,
                                           uint32_t& o0, uint32_t& o1) {
  const uint32_t ks2 = k0 ^ k1 ^ 0x1BD11BDAu;
  x0 += k0; x1 += k1;
#define TF_R(r) { x0 += x1; x1 = (x1 << (r)) | (x1 >> (32 - (r))); x1 ^= x0; }
  TF_R(13) TF_R(15) TF_R(26) TF_R(6)
  x0 += k1;  x1 += ks2 + 1u;
  TF_R(17) TF_R(29) TF_R(16) TF_R(24)
  x0 += ks2; x1 += k0 + 2u;
  TF_R(13) TF_R(15) TF_R(26) TF_R(6)
  x0 += k0;  x1 += k1 + 3u;
  TF_R(17) TF_R(29) TF_R(16) TF_R(24)
  x0 += k1;  x1 += ks2 + 4u;
  TF_R(13) TF_R(15) TF_R(26) TF_R(6)
  x0 += ks2; x1 += k0 + 5u;
#undef TF_R
  o0 = x0; o1 = x1;
}

__device__ static inline float u01(uint32_t bits) {
  return __uint_as_float((bits >> 9) | 0x3f800000u) - 1.0f;
}

// XLA ErfInv32 (Giles), fma-exact
__device__ static inline float erfinv32(float x) {
  float w = -log1pf(-x * x);
  float p;
  if (w < 5.0f) {
    w -= 2.5f;
    p = 2.81022636e-08f;
    p = fmaf(p, w, 3.43273939e-07f);
    p = fmaf(p, w, -3.5233877e-06f);
    p = fmaf(p, w, -4.39150654e-06f);
    p = fmaf(p, w, 0.00021858087f);
    p = fmaf(p, w, -0.00125372503f);
    p = fmaf(p, w, -0.00417768164f);
    p = fmaf(p, w, 0.246640727f);
    p = fmaf(p, w, 1.50140941f);
  } else {
    w = sqrtf(w) - 3.0f;
    p = -0.000200214257f;
    p = fmaf(p, w, 0.000100950558f);
    p = fmaf(p, w, 0.00134934322f);
    p = fmaf(p, w, -0.00367342844f);
    p = fmaf(p, w, 0.00573950773f);
    p = fmaf(p, w, -0.0076224613f);
    p = fmaf(p, w, 0.00943887047f);
    p = fmaf(p, w, 1.00167406f);
    p = fmaf(p, w, 2.83297682f);
  }
  return p * x;
}

__device__ static inline float norm_from_bits(uint32_t bits) {
  const float lo = __uint_as_float(0xBF7FFFFFu);       // -(1 - 2^-24)
  float u = fmaxf(lo, fmaf(u01(bits), 2.0f, lo));
  return __uint_as_float(0x3FB504F3u) * erfinv32(u);   // sqrt(2) in f32
}

__device__ static inline float r0_elem(uint32_t k0, uint32_t k1, uint32_t i) {
#if PARTITIONABLE
  uint32_t a, c; tf2(k0, k1, 0u, i, a, c);
  return norm_from_bits(a ^ c);
#else
  const uint32_t H = (uint32_t)(NCHAIN * NDIM / 2);
  uint32_t a, c;
  if (i < H) { tf2(k0, k1, i, i + H, a, c); return norm_from_bits(a); }
  else       { tf2(k0, k1, i - H, i, a, c); return norm_from_bits(c); }
#endif
}

__device__ static inline float unif_chain(uint32_t k0, uint32_t k1, int b) {
#if PARTITIONABLE
  uint32_t a, c; tf2(k0, k1, 0u, (uint32_t)b, a, c);
  return u01(a ^ c);
#else
  uint32_t a, c;
  if (b < 64) { tf2(k0, k1, (uint32_t)b, (uint32_t)(b + 64), a, c); return u01(a); }
  else        { tf2(k0, k1, (uint32_t)(b - 64), (uint32_t)b, a, c); return u01(c); }
#endif
}

// ------------------------------------------------------------- DPP sums -----
#define DPP_ADD(x, ctrl, rm)                                                   \
  (x) += __int_as_float(__builtin_amdgcn_update_dpp(                           \
      0, __float_as_int(x), (ctrl), (rm), 0xf, true));

__device__ static inline float wave_sum63(float x) {   // full 64-lane, lane 63
  DPP_ADD(x, 0x111, 0xf)   // row_shr:1
  DPP_ADD(x, 0x112, 0xf)   // row_shr:2
  DPP_ADD(x, 0x114, 0xf)   // row_shr:4
  DPP_ADD(x, 0x118, 0xf)   // row_shr:8
  DPP_ADD(x, 0x142, 0xa)   // row_bcast:15 -> rows 1,3
  DPP_ADD(x, 0x143, 0xc)   // row_bcast:31 -> rows 2,3
  return x;
}
__device__ static inline float wave_sum15(float x) {   // row-of-16 sums, lane 15 of each row
  DPP_ADD(x, 0x111, 0xf)
  DPP_ADD(x, 0x112, 0xf)
  DPP_ADD(x, 0x114, 0xf)
  DPP_ADD(x, 0x118, 0xf)
  return x;
}

// ------------------------------------------------------- float4 arithmetic --
__device__ __forceinline__ float4 f4_pcfma(float he, const float4& pc,
                                           const float4& th, const float4& r) {
  return make_float4(fmaf(he, pc.x * th.x, r.x), fmaf(he, pc.y * th.y, r.y),
                     fmaf(he, pc.z * th.z, r.z), fmaf(he, pc.w * th.w, r.w));
}
__device__ __forceinline__ float4 f4_fma(float e, const float4& a, const float4& b) {
  return make_float4(fmaf(e, a.x, b.x), fmaf(e, a.y, b.y),
                     fmaf(e, a.z, b.z), fmaf(e, a.w, b.w));
}
__device__ __forceinline__ float f4_dotsub(const float4& a, const float4& b,
                                           const float4& r) {
  float d = (a.x - b.x) * r.x;
  d = fmaf(a.y - b.y, r.y, d);
  d = fmaf(a.z - b.z, r.z, d);
  d = fmaf(a.w - b.w, r.w, d);
  return d;
}

// ------------------------------------------------------------------ params --
struct Params {
  uint32_t nk0[NNODE], nk1[NNODE];  // buildtree k3 keys, post-order across j
  uint32_t ak0[5], ak1[5];          // main-loop ka keys
  int v[5];
};

// ------------------------------- trajectory state: NAMED float4 vars only ---
struct Traj {
  float4 th, r, tho, ro, pc;
  float4 nt0, nt1, nt2, nt3, nt4;
  float4 nr0, nr1, nr2, nr3, nr4;
};
template <int L> __device__ __forceinline__ float4& NT(Traj& t) {
  if constexpr (L == 0) return t.nt0; else if constexpr (L == 1) return t.nt1;
  else if constexpr (L == 2) return t.nt2; else if constexpr (L == 3) return t.nt3;
  else return t.nt4;
}
template <int L> __device__ __forceinline__ float4& NR(Traj& t) {
  if constexpr (L == 0) return t.nr0; else if constexpr (L == 1) return t.nr1;
  else if constexpr (L == 2) return t.nr2; else if constexpr (L == 3) return t.nr3;
  else return t.nr4;
}

// store one slot's row partials (4 per wave): pos = wv4 + row
__device__ __forceinline__ void store_partial(float* __restrict__ partials,
                                              int slot, int chain, int wv4,
                                              int lane, float v) {
  if ((lane & 15) == 15)
    partials[((size_t)slot * NCHAIN + chain) * NP + wv4 + (lane >> 4)] = v;
}

// merges after a leaf: K = 0..M-1, all indices constexpr
template <int P, int K, int M>
struct Merge {
  static __device__ __forceinline__ void run(Traj& t, float* __restrict__ partials,
                                             int chain, int wv4, int lane, int& slot) {
    if constexpr (K < M) {
      const float4& nt = NT<P - 1 - K>(t);
      const float4& nr = NR<P - 1 - K>(t);
      float d1 = f4_dotsub(t.th, nt, nr);     // (th_far-th_near)·r_near
      float d2 = f4_dotsub(t.th, nt, t.r);    // (th_far-th_near)·r_far
      d1 = wave_sum15(d1);
      d2 = wave_sum15(d2);
      store_partial(partials, slot,     chain, wv4, lane, d1);
      store_partial(partials, slot + 1, chain, wv4, lane, d2);
      slot += 2;
      Merge<P, K + 1, M>::run(t, partials, chain, wv4, lane, slot);
    }
  }
};

template <int J, int I>
struct Leaf {
  static __device__ __forceinline__ void run(Traj& t, float e, float he,
                                             float* __restrict__ partials,
                                             int chain, int wv4, int lane, int& slot) {
    t.r  = f4_pcfma(-he, t.pc, t.th, t.r);
    t.th = f4_fma(e, t.r, t.th);
    t.r  = f4_pcfma(-he, t.pc, t.th, t.r);
    constexpr int P = __builtin_popcount((unsigned)I);
    NT<P>(t) = t.th; NR<P>(t) = t.r;
    constexpr int M = __builtin_ctz(~(unsigned)I);
    Merge<P, 0, M>::run(t, partials, chain, wv4, lane, slot);
    if constexpr (I + 1 < (1 << J))
      Leaf<J, I + 1>::run(t, e, he, partials, chain, wv4, lane, slot);
  }
};

// ----------------------------------------------- K1: trajectory, dots mode --
__launch_bounds__(TPB, 4)
__global__ void k_traj0(const float* __restrict__ th0g, const float* __restrict__ precg,
                        uint32_t kr0, uint32_t kr1,
                        float* __restrict__ partials, float* __restrict__ r0save,
                        Params P) {
  const int tid     = threadIdx.x;
  const int chain   = blockIdx.x / WGPC;
  const int sblk    = blockIdx.x % WGPC;
  const int dimBase = sblk * (TPB * 4) + tid * 4;
  const int lane    = tid & 63;
  const int wv4     = (sblk * 4 + (tid >> 6)) * 4;     // [0,256) step 4
  const uint32_t flat = (uint32_t)chain * NDIM + dimBase;

  Traj t;
  t.th = *reinterpret_cast<const float4*>(th0g + (size_t)chain * NDIM + dimBase);
  t.pc = *reinterpret_cast<const float4*>(precg + dimBase);
  t.r.x = r0_elem(kr0, kr1, flat + 0u);
  t.r.y = r0_elem(kr0, kr1, flat + 1u);
  t.r.z = r0_elem(kr0, kr1, flat + 2u);
  t.r.w = r0_elem(kr0, kr1, flat + 3u);
  *reinterpret_cast<float4*>(r0save + (size_t)flat) = t.r;   // for k_gather
  t.tho = t.th; t.ro = t.r;

  int slot = 0;
  bool cur_fwd = true;

#define LEVEL(J)                                                               \
  {                                                                            \
    const bool fwd = P.v[J] > 0;                                               \
    if (fwd != cur_fwd) {                                                      \
      float4 tmp;                                                              \
      tmp = t.th; t.th = t.tho; t.tho = tmp;                                   \
      tmp = t.r;  t.r  = t.ro;  t.ro  = tmp;                                   \
    }                                                                          \
    cur_fwd = fwd;                                                             \
    const float e  = fwd ? EPS : -EPS;                                         \
    const float he = 0.5f * e;                                                 \
    Leaf<J, 0>::run(t, e, he, partials, chain, wv4, lane, slot);               \
    float p1 = f4_dotsub(t.th, t.tho, t.r);                                    \
    float p2 = f4_dotsub(t.th, t.tho, t.ro);                                   \
    p1 = wave_sum15(p1);                                                       \
    p2 = wave_sum15(p2);                                                       \
    store_partial(partials, slot,     chain, wv4, lane, p1);                   \
    store_partial(partials, slot + 1, chain, wv4, lane, p2);                   \
    slot += 2;                                                                 \
  }

  LEVEL(0) LEVEL(1) LEVEL(2) LEVEL(3) LEVEL(4)
#undef LEVEL
}

// ------------------------- state machine: NAMED scalar slots + templates ----
struct SMs {
  int n0, s0, p0, n1, s1, p1, n2, s2, p2, n3, s3, p3, n4, s4, p4;
  int n, s, sel, slot, nodeidx, g;
};
template <int L> __device__ __forceinline__ int& SN(SMs& m) {
  if constexpr (L == 0) return m.n0; else if constexpr (L == 1) return m.n1;
  else if constexpr (L == 2) return m.n2; else if constexpr (L == 3) return m.n3;
  else return m.n4;
}
template <int L> __device__ __forceinline__ int& SS(SMs& m) {
  if constexpr (L == 0) return m.s0; else if constexpr (L == 1) return m.s1;
  else if constexpr (L == 2) return m.s2; else if constexpr (L == 3) return m.s3;
  else return m.s4;
}
template <int L> __device__ __forceinline__ int& SP(SMs& m) {
  if constexpr (L == 0) return m.p0; else if constexpr (L == 1) return m.p1;
  else if constexpr (L == 2) return m.p2; else if constexpr (L == 3) return m.p3;
  else return m.p4;
}

template <int P, int K, int M>
struct SMerge {
  static __device__ __forceinline__ void run(SMs& m, const float* dots_s,
                                             const float* unifs_s, float vj) {
    if constexpr (K < M) {
      constexpr int T = P - K;                       // second subtree slot
      int n1 = SN<T-1>(m), s1 = SS<T-1>(m), p1 = SP<T-1>(m);
      int n2 = SN<T>(m),   s2 = SS<T>(m),   p2 = SP<T>(m);
      float d1 = dots_s[m.slot], d2 = dots_s[m.slot + 1];
      m.slot += 2;
      float uu = unifs_s[m.nodeidx]; m.nodeidx++;
      int dn = n1 + n2; if (dn < 1) dn = 1;
      bool fl = (uu < (float)n2 / (float)dn) && (s1 >= 1);
      SP<T-1>(m) = fl ? p2 : p1;
      SS<T-1>(m) = (s1 != 0 && s2 != 0 &&
                    (vj * d1 >= 0.0f) && (vj * d2 >= 0.0f)) ? 1 : 0;
      SN<T-1>(m) = n1 + ((s1 >= 1) ? n2 : 0);
      SMerge<P, K + 1, M>::run(m, dots_s, unifs_s, vj);
    }
  }
};

template <int J, int I>
struct SLeaf {
  static __device__ __forceinline__ void run(SMs& m, const float* dots_s,
                                             const float* unifs_s, float vj) {
    constexpr int P = __builtin_popcount((unsigned)I);
    SN<P>(m) = 1; SS<P>(m) = 1; SP<P>(m) = m.g; m.g++;
    constexpr int M = __builtin_ctz(~(unsigned)I);
    SMerge<P, 0, M>::run(m, dots_s, unifs_s, vj);
    if constexpr (I + 1 < (1 << J))
      SLeaf<J, I + 1>::run(m, dots_s, unifs_s, vj);
  }
};

template <int J>
__device__ __forceinline__ void sm_close(SMs& m, const float* dots_s,
                                         const float* unifs_s, int vj) {
  int n_p = SN<0>(m), s_p = SS<0>(m), th_p = SP<0>(m);
  float q1 = dots_s[m.slot], q2 = dots_s[m.slot + 1];  // (a-o)·r_a, (a-o)·r_o
  m.slot += 2;
  float dm1, dm2;                                      // d = (th_f - th_r)
  if (vj > 0) { dm1 = q2;  dm2 = q1; }
  else        { dm1 = -q1; dm2 = -q2; }
  float au = unifs_s[NNODE + J];
  float ratio = fminf((float)n_p / (float)m.n, 1.0f);
  bool acc = (au < ratio) && (m.s >= 1) && (s_p >= 1);
  if (acc) m.sel = th_p;
  m.n = m.n + ((m.s >= 1) ? n_p : 0);
  m.s = (m.s != 0 && s_p != 0 && (dm1 >= 0.0f) && (dm2 >= 0.0f)) ? 1 : 0;
}

// --------- K2: per-block reduce + state machine + gather (2048 blocks) ------
__launch_bounds__(TPB, 4)
__global__ void k_gather(const float* __restrict__ th0g, const float* __restrict__ precg,
                         const float* __restrict__ partials, const float* __restrict__ r0save,
                         float* __restrict__ outg, Params P) {
  __shared__ float dots_s[NSLOT];
  __shared__ float unifs_s[NNODE + 5];

  const int tid     = threadIdx.x;
  const int chain   = blockIdx.x / WGPC;
  const int sblk    = blockIdx.x % WGPC;
  const int dimBase = sblk * (TPB * 4) + tid * 4;
  const size_t off  = (size_t)chain * NDIM + dimBase;
  const int lane    = tid & 63;
  const int w       = tid >> 6;

  // ---- reduce this chain's partials into LDS (redundant per block) ---------
  for (int s = w; s < NSLOT; s += TPB / 64) {
    const float4 v4 = *reinterpret_cast<const float4*>(
        partials + ((size_t)s * NCHAIN + chain) * NP + lane * 4);
    float v = (v4.x + v4.y) + (v4.z + v4.w);
    v = wave_sum63(v);
    if (lane == 63) dots_s[s] = v;
  }
  if (tid < NNODE) unifs_s[tid] = unif_chain(P.nk0[tid], P.nk1[tid], chain);
  else if (tid < NNODE + 5)
    unifs_s[tid] = unif_chain(P.ak0[tid - NNODE], P.ak1[tid - NNODE], chain);
  __syncthreads();

  // ---- state machine (all threads, LDS broadcast reads) --------------------
  SMs m;
  m.n = 1; m.s = 1; m.sel = -1; m.slot = 0; m.nodeidx = 0; m.g = 0;
#define SLEVEL(J)                                                              \
  {                                                                            \
    const float vj = (P.v[J] > 0) ? 1.0f : -1.0f;                              \
    SLeaf<J, 0>::run(m, dots_s, unifs_s, vj);                                  \
    sm_close<J>(m, dots_s, unifs_s, P.v[J]);                                   \
  }
  SLEVEL(0) SLEVEL(1) SLEVEL(2) SLEVEL(3) SLEVEL(4)
#undef SLEVEL
  const int sel = m.sel;

  // ---- re-simulate to the selected leaf, write ----------------------------
  float4 th = *reinterpret_cast<const float4*>(th0g + off);
  float4 outv = th;                                    // default: theta0
  if (sel >= 0) {
    float4 pc = *reinterpret_cast<const float4*>(precg + dimBase);
    float4 r  = *reinterpret_cast<const float4*>(r0save + off);
    float4 tho = th, ro = r;
    int g = 0;
    bool cur_fwd = true;
    bool fin = false;
    for (int j = 0; j < 5 && !fin; ++j) {
      const bool fwd = P.v[j] > 0;
      if (fwd != cur_fwd) {
        float4 tmp;
        tmp = th; th = tho; tho = tmp;
        tmp = r;  r  = ro;  ro  = tmp;
      }
      cur_fwd = fwd;
      const float e  = fwd ? EPS : -EPS;
      const float he = 0.5f * e;
      const int NL = 1 << j;
      for (int i = 0; i < NL; ++i) {
        r  = f4_pcfma(-he, pc, th, r);
        th = f4_fma(e, r, th);
        r  = f4_pcfma(-he, pc, th, r);
        if (g == sel) { outv = th; fin = true; break; }
        g++;
      }
    }
  }
  *reinterpret_cast<float4*>(outg + off) = outv;
}

// ------------------------------------------------------------- host PRNG ---
static inline float host_bits_to_f(uint32_t fb) { float f; std::memcpy(&f, &fb, 4); return f; }

static void host_split(uint32_t k0, uint32_t k1, int nsub, uint32_t* o0, uint32_t* o1) {
#if PARTITIONABLE
  for (int i = 0; i < nsub; ++i) tf2(k0, k1, 0u, (uint32_t)i, o0[i], o1[i]);
#else
  uint32_t A[8], C[8], flat[16];
  for (int i = 0; i < nsub; ++i) tf2(k0, k1, (uint32_t)i, (uint32_t)(nsub + i), A[i], C[i]);
  for (int i = 0; i < nsub; ++i) { flat[i] = A[i]; flat[nsub + i] = C[i]; }
  for (int j = 0; j < nsub; ++j) { o0[j] = flat[2*j]; o1[j] = flat[2*j + 1]; }
#endif
}

static int host_vsign(uint32_t k0, uint32_t k1) {    // sign of normal(kv, ())
  uint32_t a, c; tf2(k0, k1, 0u, 0u, a, c);
#if PARTITIONABLE
  uint32_t bits = a ^ c;
#else
  uint32_t bits = a;
#endif
  float f  = host_bits_to_f((bits >> 9) | 0x3f800000u) - 1.0f;
  float lo = host_bits_to_f(0xBF7FFFFFu);
  float u  = f * 2.0f + lo;                          // sign(erfinv(u)) = sign(u)
  return (u >= 0.0f) ? 1 : -1;
}

// buildtree k3 keys in post-order (merge-consumption order)
static void gen_nodes(uint32_t k0, uint32_t k1, int j,
                      uint32_t* nk0, uint32_t* nk1, int& idx) {
  if (j == 0) return;
  uint32_t o0[3], o1[3];
  host_split(k0, k1, 3, o0, o1);                     // k1, k2, k3
  gen_nodes(o0[0], o1[0], j - 1, nk0, nk1, idx);
  gen_nodes(o0[1], o1[1], j - 1, nk0, nk1, idx);
  nk0[idx] = o0[2]; nk1[idx] = o1[2]; idx++;
}

// ---------------------------------------------------------------- launch ----
extern "C" void kernel_launch(void* const* d_in, const int* in_sizes, int n_in,
                              void* d_out, int out_size, void* d_ws, size_t ws_size,
                              hipStream_t stream) {
  const float* th0  = (const float*)d_in[0];
  const float* prec = (const float*)d_in[1];
  float* out = (float*)d_out;

  float* partials = (float*)d_ws;                               // 62*128*256*4 ~ 8.1 MB
  float* r0save   = partials + (size_t)NSLOT * NCHAIN * NP;     // 8 MB

  // ---- replicate jax key schedule on host (deterministic, same every call)
  uint32_t key0 = 0u, key1 = 42u;                               // jax.random.key(42)
  uint32_t s0[4], s1[4];
  host_split(key0, key1, 3, s0, s1);                            // kr, ku, key
  const uint32_t kr0 = s0[0], kr1 = s1[0];                      // r0 normals
  key0 = s0[2]; key1 = s1[2];                                   // (ku unused: u==0)

  Params P;
  int idx = 0;
  for (int j = 0; j < 5; ++j) {
    host_split(key0, key1, 4, s0, s1);                          // key, kv, kt, ka
    key0 = s0[0]; key1 = s1[0];
    P.v[j] = host_vsign(s0[1], s1[1]);
    gen_nodes(s0[2], s1[2], j, P.nk0, P.nk1, idx);              // kt recursion
    P.ak0[j] = s0[3]; P.ak1[j] = s1[3];                         // ka
  }

  k_traj0<<<dim3(NCHAIN * WGPC), dim3(TPB), 0, stream>>>(
      th0, prec, kr0, kr1, partials, r0save, P);
  k_gather<<<dim3(NCHAIN * WGPC), dim3(TPB), 0, stream>>>(
      th0, prec, partials, r0save, out, P);
}